// Round 3
// baseline (1444.791 us; speedup 1.0000x reference)
//
#include <hip/hip_runtime.h>
#include <math.h>

#define EPSF 1e-6f

#define NL 4
#define NB 8
#define NE 1024
#define NH 16
#define ND 64
#define NG 4096
#define NIMG 256
#define NTT 64
#define NV 16385

// ---- workspace float offsets ----
// atomic (zeroed each call) region:
#define AX    0          // x[1..4], 4*8192
#define AQS   32768      // q_self[4][8192]
#define AKV   65536      // kv[4][16*1024]
#define ASS   131072     // s_self[4][8192]
#define AQE   163840     // q_enc[4][8192]
#define AOE   196608     // o_enc[4][8192]
#define ASE   229376     // s_enc[4][8192]
#define AGA   262144     // gA[4][32768]
#define AGB   393216     // gB[4][32768]
#define AEND  524288
// direct-write region:
#define DX0   524288
#define DAT   532480
#define DX2   540672
#define DX3   548864
#define DG    557056     // 8*4096

__device__ inline void wave_red2(float& a, float& b) {
#pragma unroll
  for (int o = 32; o; o >>= 1) { a += __shfl_xor(a, o); b += __shfl_xor(b, o); }
}

// ---------------- float4 matvec: out[m][8][N] += h[8][k-slice] @ W[m][k-slice] ----------------
// Each thread owns 4 consecutive cols (float4 weight loads). Block covers 1024 cols x BK rows.
// mode 0: h = xin slice (no LN)
// mode 1: h = LN(xin; lns2 (opt), lnb2), width K
// mode 2: x2 = xin + LN(sres; lns1, lnb1); h = LN(x2; lnb2); block 0 writes x2store (K=1024)
struct Mv4P {
  const float* W0; const float* W1; const float* W2;
  float* out0; float* out1; float* out2;
  const float* xin;
  const float* sres;
  const float* lnb1; const float* lns1;
  const float* lnb2; const float* lns2;
  float* x2store;
  const float* resid;   // added once (ks==0)
  int K, N, CB, KS, mode;
};

__global__ __launch_bounds__(256) void mv4_kernel(Mv4P p) {
  __shared__ float h[8 * 128];
  const int tid = threadIdx.x, wv = tid >> 6, ln = tid & 63;
  const int per = p.CB * p.KS;
  const int m = blockIdx.x / per, rem = blockIdx.x % per;
  const int ks = rem / p.CB, cb = rem % p.CB;
  const int BK = p.K / p.KS;
  const int k0 = ks * BK;
  const int n0 = cb * 1024;

  if (p.mode == 0) {
    for (int i = tid; i < 8 * BK; i += 256) {
      int r = i / BK, kk = i - r * BK;
      h[r * BK + kk] = p.xin[(size_t)r * p.K + k0 + kk];
    }
  } else if (p.mode == 1) {
    for (int r = wv; r < 8; r += 4) {
      const float* xr = p.xin + (size_t)r * p.K;
      float s = 0.f, ss = 0.f;
      for (int i = ln; i < p.K; i += 64) { float v = xr[i]; s += v; ss += v * v; }
      wave_red2(s, ss);
      float mean = s / p.K, var = ss / p.K - mean * mean, rs = rsqrtf(var + EPSF);
      for (int i = k0 + ln; i < k0 + BK; i += 64) {
        float sc = p.lns2 ? p.lns2[i] : 1.f;
        h[r * BK + (i - k0)] = (xr[i] - mean) * rs * sc + p.lnb2[i];
      }
    }
  } else {  // mode 2, K == 1024
    for (int r = wv; r < 8; r += 4) {
      const float* xr = p.xin + (size_t)r * 1024;
      const float* sr = p.sres + (size_t)r * 1024;
      float s = 0.f, ss = 0.f;
      for (int i = ln; i < 1024; i += 64) { float v = sr[i]; s += v; ss += v * v; }
      wave_red2(s, ss);
      float m1 = s / 1024.f, rs1 = rsqrtf(ss / 1024.f - m1 * m1 + EPSF);
      float s2 = 0.f, ss2 = 0.f;
      for (int i = ln; i < 1024; i += 64) {
        float sc = p.lns1 ? p.lns1[i] : 1.f;
        float v = xr[i] + (sr[i] - m1) * rs1 * sc + p.lnb1[i];
        s2 += v; ss2 += v * v;
      }
      wave_red2(s2, ss2);
      float m2 = s2 / 1024.f, rs2 = rsqrtf(ss2 / 1024.f - m2 * m2 + EPSF);
      for (int i = k0 + ln; i < k0 + BK; i += 64) {
        float sc = p.lns1 ? p.lns1[i] : 1.f;
        float v = xr[i] + (sr[i] - m1) * rs1 * sc + p.lnb1[i];
        h[r * BK + (i - k0)] = (v - m2) * rs2 + p.lnb2[i];
      }
      if (p.x2store && blockIdx.x == 0) {
        for (int i = ln; i < 1024; i += 64) {
          float sc = p.lns1 ? p.lns1[i] : 1.f;
          p.x2store[r * 1024 + i] = xr[i] + (sr[i] - m1) * rs1 * sc + p.lnb1[i];
        }
      }
    }
  }
  __syncthreads();

  const int nb = n0 + tid * 4;
  if (nb >= p.N) return;
  const float* W = (m == 0) ? p.W0 : (m == 1) ? p.W1 : p.W2;
  float* out = (m == 0) ? p.out0 : (m == 1) ? p.out1 : p.out2;
  const float* wp = W + (size_t)k0 * p.N + nb;
  const bool addres = (p.resid != nullptr) && (ks == 0);

  if (nb + 3 < p.N) {
    float4 acc[8];
#pragma unroll
    for (int r = 0; r < 8; ++r) acc[r] = make_float4(0.f, 0.f, 0.f, 0.f);
#pragma unroll 4
    for (int kk = 0; kk < BK; ++kk) {
      float4 w = *reinterpret_cast<const float4*>(wp + (size_t)kk * p.N);
#pragma unroll
      for (int r = 0; r < 8; ++r) {
        float hv = h[r * BK + kk];
        acc[r].x += hv * w.x; acc[r].y += hv * w.y;
        acc[r].z += hv * w.z; acc[r].w += hv * w.w;
      }
    }
#pragma unroll
    for (int r = 0; r < 8; ++r) {
      float4 a = acc[r];
      if (addres) {
        const float* rr = p.resid + (size_t)r * p.N + nb;
        a.x += rr[0]; a.y += rr[1]; a.z += rr[2]; a.w += rr[3];
      }
      float* op = out + (size_t)r * p.N + nb;
      atomicAdd(op + 0, a.x); atomicAdd(op + 1, a.y);
      atomicAdd(op + 2, a.z); atomicAdd(op + 3, a.w);
    }
  } else {
    for (int c = 0; c < 4; ++c) {
      if (nb + c >= p.N) break;
      float acc[8] = {0.f, 0.f, 0.f, 0.f, 0.f, 0.f, 0.f, 0.f};
      for (int kk = 0; kk < BK; ++kk) {
        float w = wp[(size_t)kk * p.N + c];
#pragma unroll
        for (int r = 0; r < 8; ++r) acc[r] += h[r * BK + kk] * w;
      }
#pragma unroll
      for (int r = 0; r < 8; ++r) {
        float a = acc[r];
        if (addres) a += p.resid[(size_t)r * p.N + nb + c];
        atomicAdd(out + (size_t)r * p.N + nb + c, a);
      }
    }
  }
}

// ---------------- ast passthrough copy ----------------
__global__ void copy_ast(const float4* __restrict__ in, float4* __restrict__ out, int n4) {
  int i = blockIdx.x * blockDim.x + threadIdx.x;
  int st = gridDim.x * blockDim.x;
  for (; i < n4; i += st) out[i] = in[i];
}

// ---------------- embedding + LN ----------------
__global__ __launch_bounds__(256) void embed_kernel(const float* __restrict__ tok,
    const float* __restrict__ pos, const int* __restrict__ prev, const int* __restrict__ tixp,
    const float* __restrict__ lnb, const float* __restrict__ lns, float* __restrict__ x0) {
  int b = blockIdx.x;
  const float* te = tok + (size_t)prev[0] * NE;
  const float* pe = pos + (size_t)tixp[0] * NE;
  __shared__ float row[NE];
  __shared__ float aa[4], bb[4];
  int tid = threadIdx.x;
  float s = 0.f, ss = 0.f;
  for (int i = tid; i < NE; i += 256) { float v = te[i] + pe[i]; row[i] = v; s += v; ss += v * v; }
  wave_red2(s, ss);
  if ((tid & 63) == 0) { aa[tid >> 6] = s; bb[tid >> 6] = ss; }
  __syncthreads();
  s = aa[0] + aa[1] + aa[2] + aa[3]; ss = bb[0] + bb[1] + bb[2] + bb[3];
  float m = s / NE, var = ss / NE - m * m, rs = rsqrtf(var + EPSF);
  for (int i = tid; i < NE; i += 256) x0[(size_t)b * NE + i] = (row[i] - m) * rs * lns[i] + lnb[i];
}

// ---------------- self attention core ----------------
__global__ __launch_bounds__(256) void self_attn_kernel(const float* __restrict__ q_self,
    const float* __restrict__ kvf, const float* __restrict__ ast, const int* __restrict__ tixp,
    float* __restrict__ attnout) {
  int b = blockIdx.x >> 4, hh = blockIdx.x & 15;
  int tid = threadIdx.x;
  int tix = tixp[0];
  int T = tix + 1; if (T > NIMG) T = NIMG;
  __shared__ float qv[64];
  __shared__ float sc[256];
  __shared__ float red[256];
  if (tid < 64) qv[tid] = q_self[(size_t)b * NE + hh * 64 + tid] * 0.125f;
  __syncthreads();
  float sj = -INFINITY;
  if (tid < T) {
    const float* kr = (tid == tix) ? (kvf + (size_t)b * NE + hh * 64)
                                   : (ast + ((size_t)b * NIMG + tid) * NE + hh * 64);
    float s = 0.f;
#pragma unroll
    for (int d0 = 0; d0 < 64; d0 += 4) {
      float4 k4 = *reinterpret_cast<const float4*>(kr + d0);
      s += qv[d0] * k4.x + qv[d0 + 1] * k4.y + qv[d0 + 2] * k4.z + qv[d0 + 3] * k4.w;
    }
    sj = s;
  }
  red[tid] = sj; __syncthreads();
  for (int o = 128; o; o >>= 1) { if (tid < o) red[tid] = fmaxf(red[tid], red[tid + o]); __syncthreads(); }
  float mx = red[0]; __syncthreads();
  float e = (tid < T) ? __expf(sj - mx) : 0.f;
  red[tid] = e; __syncthreads();
  for (int o = 128; o; o >>= 1) { if (tid < o) red[tid] += red[tid + o]; __syncthreads(); }
  float inv = 1.f / red[0];
  sc[tid] = e * inv;
  __syncthreads();
  int d = tid & 63, jc = tid >> 6;
  float part = 0.f;
  for (int j = jc; j < T; j += 4) {
    const float* vr = (j == tix) ? (kvf + (size_t)(8 + b) * NE + hh * 64)
                                 : (ast + ((size_t)(8 + b) * NIMG + j) * NE + hh * 64);
    part += sc[j] * vr[d];
  }
  red[tid] = part; __syncthreads();
  if (tid < 64)
    attnout[(size_t)b * NE + hh * 64 + tid] = red[tid] + red[tid + 64] + red[tid + 128] + red[tid + 192];
}

// ---------------- fused cross attention: qW -> scores -> softmax -> wX -> o_enc ----------------
__global__ __launch_bounds__(256) void cross_fused_kernel(const float* __restrict__ q_enc,
    const float* __restrict__ Wk, const float* __restrict__ Wv, const float* __restrict__ X,
    const void* __restrict__ maskp, float* __restrict__ o_enc) {
  int b = blockIdx.x >> 4, hh = blockIdx.x & 15;
  int tid = threadIdx.x;
  __shared__ float qv[64];
  __shared__ float qwl[NE];    // reused later for oenc partials
  __shared__ float wxl[NE];
  __shared__ float red[256];
  __shared__ float w_[NTT];
  __shared__ int mask_i32;
  if (tid == 0) {
    const unsigned int* w = (const unsigned int*)maskp;
    int i32 = 1;
    for (int j = 0; j < 128; ++j) { if (w[j] > 1u) { i32 = 0; break; } }
    mask_i32 = i32;
  }
  if (tid < 64) qv[tid] = q_enc[(size_t)b * NE + hh * 64 + tid];
  __syncthreads();

  // qW[e] = sum_d qv[d] * Wk[e, hh*64+d]
#pragma unroll
  for (int j = 0; j < 4; ++j) {
    int e = tid + 256 * j;
    const float* wr = Wk + (size_t)e * NE + hh * 64;
    float a = 0.f;
#pragma unroll
    for (int d0 = 0; d0 < 64; d0 += 4) {
      float4 w4 = *reinterpret_cast<const float4*>(wr + d0);
      a += qv[d0] * w4.x + qv[d0 + 1] * w4.y + qv[d0 + 2] * w4.z + qv[d0 + 3] * w4.w;
    }
    qwl[e] = a;
  }
  __syncthreads();

  // scores[t] = 0.125 * sum_e qwl[e] * X[b,t,e]
  int t = tid & 63, ec = tid >> 6;
  const float* xr = X + ((size_t)b * NTT + t) * NE + ec * 256;
  float part = 0.f;
#pragma unroll 4
  for (int i = 0; i < 256; i += 4) {
    float4 x4 = *reinterpret_cast<const float4*>(xr + i);
    part += qwl[ec * 256 + i] * x4.x + qwl[ec * 256 + i + 1] * x4.y +
            qwl[ec * 256 + i + 2] * x4.z + qwl[ec * 256 + i + 3] * x4.w;
  }
  red[ec * 64 + t] = part; __syncthreads();
  float sco = -INFINITY;
  if (tid < 64) {
    float s = (red[tid] + red[64 + tid] + red[128 + tid] + red[192 + tid]) * 0.125f;
    int idx = b * NTT + tid;
    bool valid = mask_i32 ? (((const int*)maskp)[idx] != 0)
                          : (((const unsigned char*)maskp)[idx] != 0);
    sco = valid ? s : -INFINITY;
  }
  __syncthreads();
  red[tid] = (tid < 64) ? sco : -INFINITY; __syncthreads();
  for (int o = 128; o; o >>= 1) { if (tid < o) red[tid] = fmaxf(red[tid], red[tid + o]); __syncthreads(); }
  float mx = red[0]; __syncthreads();
  float e = (tid < 64) ? __expf(sco - mx) : 0.f;
  red[tid] = e; __syncthreads();
  for (int o = 128; o; o >>= 1) { if (tid < o) red[tid] += red[tid + o]; __syncthreads(); }
  if (tid < 64) w_[tid] = e / red[0];
  __syncthreads();

  // wX[e] = sum_t w_[t] * X[b,t,e]  (thread owns 4 consecutive e)
  {
    float4 a = make_float4(0.f, 0.f, 0.f, 0.f);
    for (int t2 = 0; t2 < NTT; ++t2) {
      float wt = w_[t2];
      float4 x4 = *reinterpret_cast<const float4*>(X + ((size_t)b * NTT + t2) * NE + tid * 4);
      a.x += wt * x4.x; a.y += wt * x4.y; a.z += wt * x4.z; a.w += wt * x4.w;
    }
    reinterpret_cast<float4*>(wxl)[tid] = a;
  }
  __syncthreads();

  // o_enc[b, hh*64+d] = sum_e wxl[e] * Wv[e, hh*64+d]
  {
    int d4 = (tid & 15) * 4, ech = tid >> 4;  // 16 chunks of 64 e
    float4 a = make_float4(0.f, 0.f, 0.f, 0.f);
    for (int e2 = ech * 64; e2 < ech * 64 + 64; ++e2) {
      float wx = wxl[e2];
      float4 wv4 = *reinterpret_cast<const float4*>(Wv + (size_t)e2 * NE + hh * 64 + d4);
      a.x += wx * wv4.x; a.y += wx * wv4.y; a.z += wx * wv4.z; a.w += wx * wv4.w;
    }
    qwl[ech * 64 + d4 + 0] = a.x; qwl[ech * 64 + d4 + 1] = a.y;
    qwl[ech * 64 + d4 + 2] = a.z; qwl[ech * 64 + d4 + 3] = a.w;
  }
  __syncthreads();
  if (tid < 64) {
    float o = 0.f;
#pragma unroll
    for (int ech = 0; ech < 16; ++ech) o += qwl[ech * 64 + tid];
    o_enc[(size_t)b * NE + hh * 64 + tid] = o;
  }
}

// ---------------- g = gelu(a) * b ----------------
__global__ void gelu_mul_kernel(const float* __restrict__ a, const float* __restrict__ b,
                                float* __restrict__ g, int n) {
  int i = blockIdx.x * blockDim.x + threadIdx.x;
  if (i < n) { float x = a[i]; g[i] = 0.5f * x * (1.f + erff(x * 0.70710678118f)) * b[i]; }
}

// ---------------- write fresh k,v rows into output attention_state ----------------
__global__ void kv_out_kernel(const float* __restrict__ kv, float* __restrict__ out_ast,
                              const int* __restrict__ tixp) {
  int l = blockIdx.x >> 4, r = blockIdx.x & 15;
  int tix = tixp[0];
  const float* src = kv + (size_t)(l * 16 + r) * NE;
  float* dst = out_ast + (((size_t)(l * 16 + r)) * NIMG + tix) * NE;
  for (int i = threadIdx.x; i < NE; i += 256) dst[i] = src[i];
}

extern "C" void kernel_launch(void* const* d_in, const int* in_sizes, int n_in,
                              void* d_out, int out_size, void* d_ws, size_t ws_size,
                              hipStream_t stream) {
  const float* enc_state = (const float*)d_in[0];
  const float* ast_in    = (const float*)d_in[1];
  const void* amask      = d_in[2];
  const int* prev = (const int*)d_in[3];
  const int* tix  = (const int*)d_in[4];
  const float* embed_tok = (const float*)d_in[5];
  const float* embed_pos = (const float*)d_in[6];
  const float* lnemb_s = (const float*)d_in[7];
  const float* lnemb_b = (const float*)d_in[8];
  const float* psb = (const float*)d_in[9];
  const float* Wsq = (const float*)d_in[10];
  const float* Wsk = (const float*)d_in[11];
  const float* Wsv = (const float*)d_in[12];
  const float* Wso = (const float*)d_in[13];
  const float* sls = (const float*)d_in[14];
  const float* slb = (const float*)d_in[15];
  const float* peb = (const float*)d_in[16];
  const float* Weq = (const float*)d_in[17];
  const float* Wek = (const float*)d_in[18];
  const float* Wev = (const float*)d_in[19];
  const float* Weo = (const float*)d_in[20];
  const float* els = (const float*)d_in[21];
  const float* elb = (const float*)d_in[22];
  const float* g0b = (const float*)d_in[23];
  const float* Wf0 = (const float*)d_in[24];
  const float* Wf1 = (const float*)d_in[25];
  const float* g1b = (const float*)d_in[26];
  const float* Wf2 = (const float*)d_in[27];
  const float* flb = (const float*)d_in[28];
  const float* Wlm = (const float*)d_in[29];

  float* ws = (float*)d_ws;
  float* logits = (float*)d_out;
  float* out_ast = logits + (size_t)NB * NV;

  hipMemsetAsync(d_ws, 0, AEND * sizeof(float), stream);
  hipMemsetAsync(d_out, 0, (size_t)NB * NV * sizeof(float), stream);

  copy_ast<<<4096, 256, 0, stream>>>((const float4*)ast_in, (float4*)out_ast, NL * 16 * NIMG * NE / 4);
  embed_kernel<<<NB, 256, 0, stream>>>(embed_tok, embed_pos, prev, tix, lnemb_b, lnemb_s, ws + DX0);

  for (int l = 0; l < NL; ++l) {
    float* xl  = (l == 0) ? (ws + DX0) : (ws + AX + (size_t)(l - 1) * 8192);
    float* xn  = ws + AX + (size_t)l * 8192;
    float* kvl = ws + AKV + (size_t)l * 16384;
    float* qsl = ws + AQS + (size_t)l * 8192;
    float* ssl = ws + ASS + (size_t)l * 8192;
    float* qel = ws + AQE + (size_t)l * 8192;
    float* oel = ws + AOE + (size_t)l * 8192;
    float* sel = ws + ASE + (size_t)l * 8192;
    float* gal = ws + AGA + (size_t)l * 32768;
    float* gbl = ws + AGB + (size_t)l * 32768;
    size_t wE = (size_t)l * NE * NE;
    size_t wG = (size_t)l * NE * NG;

    {  // a: LN(x, psb) then k,v,q projections
      Mv4P p{}; p.W0 = Wsk + wE; p.W1 = Wsv + wE; p.W2 = Wsq + wE;
      p.out0 = kvl; p.out1 = kvl + 8 * NE; p.out2 = qsl;
      p.xin = xl; p.lnb2 = psb + (size_t)l * NE; p.lns2 = nullptr;
      p.K = NE; p.N = NE; p.CB = 1; p.KS = 32; p.mode = 1;
      mv4_kernel<<<3 * 32, 256, 0, stream>>>(p);
    }
    self_attn_kernel<<<NB * NH, 256, 0, stream>>>(qsl, kvl, ast_in + (size_t)l * 16 * NIMG * NE, tix, ws + DAT);
    {  // c: attnout @ so
      Mv4P p{}; p.W0 = Wso + wE; p.out0 = ssl; p.xin = ws + DAT;
      p.K = NE; p.N = NE; p.CB = 1; p.KS = 32; p.mode = 0;
      mv4_kernel<<<32, 256, 0, stream>>>(p);
    }
    {  // d: x2 = x + LN(s_self); h = LN(x2, peb); q_enc = h @ eq
      Mv4P p{}; p.W0 = Weq + wE; p.out0 = qel; p.xin = xl; p.sres = ssl;
      p.lnb1 = slb + (size_t)l * NE; p.lns1 = sls + (size_t)l * NE; p.lnb2 = peb + (size_t)l * NE;
      p.x2store = ws + DX2;
      p.K = NE; p.N = NE; p.CB = 1; p.KS = 32; p.mode = 2;
      mv4_kernel<<<32, 256, 0, stream>>>(p);
    }
    cross_fused_kernel<<<NB * NH, 256, 0, stream>>>(qel, Wek + wE, Wev + wE, enc_state, amask, oel);
    {  // h: o_enc @ eo
      Mv4P p{}; p.W0 = Weo + wE; p.out0 = sel; p.xin = oel;
      p.K = NE; p.N = NE; p.CB = 1; p.KS = 32; p.mode = 0;
      mv4_kernel<<<32, 256, 0, stream>>>(p);
    }
    {  // i: x3 = x2 + LN(s_enc); h = LN(x3, g0b); gA = h@fc0, gB = h@fc1
      Mv4P p{}; p.W0 = Wf0 + wG; p.W1 = Wf1 + wG; p.out0 = gal; p.out1 = gbl;
      p.xin = ws + DX2; p.sres = sel;
      p.lnb1 = elb + (size_t)l * NE; p.lns1 = els + (size_t)l * NE; p.lnb2 = g0b + (size_t)l * NE;
      p.x2store = ws + DX3;
      p.K = NE; p.N = NG; p.CB = 4; p.KS = 16; p.mode = 2;
      mv4_kernel<<<2 * 16 * 4, 256, 0, stream>>>(p);
    }
    gelu_mul_kernel<<<128, 256, 0, stream>>>(gal, gbl, ws + DG, NB * NG);
    {  // k: h = LN(g, g1b); x_{l+1} = x3 + h @ fc2
      Mv4P p{}; p.W0 = Wf2 + (size_t)l * NG * NE; p.out0 = xn; p.xin = ws + DG;
      p.lnb2 = g1b + (size_t)l * NG; p.lns2 = nullptr; p.resid = ws + DX3;
      p.K = NG; p.N = NE; p.CB = 1; p.KS = 32; p.mode = 1;
      mv4_kernel<<<32, 256, 0, stream>>>(p);
    }
  }
  {  // final: logits = LN(x4, final_ln_b) @ lm_head
    Mv4P p{}; p.W0 = Wlm; p.out0 = logits; p.xin = ws + AX + 3 * 8192;
    p.lnb2 = flb; p.lns2 = nullptr;
    p.K = NE; p.N = NV; p.CB = 17; p.KS = 16; p.mode = 1;
    mv4_kernel<<<17 * 16, 256, 0, stream>>>(p);
  }
  kv_out_kernel<<<NL * 16, 256, 0, stream>>>(ws + AKV, out_ast, tix);
}

// Round 4
// 764.180 us; speedup vs baseline: 1.8906x; 1.8906x over previous
//
#include <hip/hip_runtime.h>
#include <math.h>

#define EPSF 1e-6f

#define NL 4
#define NB 8
#define NE 1024
#define NH 16
#define NG 4096
#define NIMG 256
#define NTT 64
#define NV 16385

// ---- workspace float offsets ----
// atomic (zeroed each call) region:
#define AX    0          // x_next[4][8192]
#define AQS   32768      // q_self[4][8192]
#define AKV   65536      // kv[4][16384]
#define ASS   131072     // s_self[4][8192]
#define ASE   163840     // s_enc[4][8192]
#define AGA   196608     // gA[4][32768]
#define AGB   327680     // gB[4][32768]
#define AEND  458752
// direct-write region (reused across layers):
#define DX0   458752
#define DH1   466944
#define DX2   475136
#define DH2   483328
#define DX3   491520
#define DH3   499712
#define DHG   507904     // 8*4096
#define DHF   540672

__device__ inline void wave_red2(float& a, float& b) {
#pragma unroll
  for (int o = 32; o; o >>= 1) { a += __shfl_xor(a, o); b += __shfl_xor(b, o); }
}

__device__ inline void block_red2(float& s, float& ss, float* tmp) {
  wave_red2(s, ss);
  int wv = threadIdx.x >> 6, ln = threadIdx.x & 63;
  if (ln == 0) { tmp[wv] = s; tmp[4 + wv] = ss; }
  __syncthreads();
  s = tmp[0] + tmp[1] + tmp[2] + tmp[3];
  ss = tmp[4] + tmp[5] + tmp[6] + tmp[7];
  __syncthreads();
}

// ---------------- LN kernels (row-parallel, 8 blocks) ----------------
__global__ __launch_bounds__(256) void ln_simple(const float* __restrict__ src,
    const float* __restrict__ scale, const float* __restrict__ bias, float* __restrict__ dst) {
  __shared__ float tmp[8];
  int b = blockIdx.x, tid = threadIdx.x;
  float4 v = *reinterpret_cast<const float4*>(src + (size_t)b * NE + tid * 4);
  float s = v.x + v.y + v.z + v.w;
  float ss = v.x * v.x + v.y * v.y + v.z * v.z + v.w * v.w;
  block_red2(s, ss, tmp);
  float m = s / NE, rs = rsqrtf(ss / NE - m * m + EPSF);
  float4 bi = *reinterpret_cast<const float4*>(bias + tid * 4);
  float4 o;
  if (scale) {
    float4 sc = *reinterpret_cast<const float4*>(scale + tid * 4);
    o.x = (v.x - m) * rs * sc.x + bi.x; o.y = (v.y - m) * rs * sc.y + bi.y;
    o.z = (v.z - m) * rs * sc.z + bi.z; o.w = (v.w - m) * rs * sc.w + bi.w;
  } else {
    o.x = (v.x - m) * rs + bi.x; o.y = (v.y - m) * rs + bi.y;
    o.z = (v.z - m) * rs + bi.z; o.w = (v.w - m) * rs + bi.w;
  }
  *reinterpret_cast<float4*>(dst + (size_t)b * NE + tid * 4) = o;
}

// xstore = xres + LN(sres; lns1, lnb1);  hout = LN(xstore) + lnb2
__global__ __launch_bounds__(256) void ln_res(const float* __restrict__ xres,
    const float* __restrict__ sres, const float* __restrict__ lns1,
    const float* __restrict__ lnb1, const float* __restrict__ lnb2,
    float* __restrict__ xstore, float* __restrict__ hout) {
  __shared__ float tmp[8];
  int b = blockIdx.x, tid = threadIdx.x;
  float4 xv = *reinterpret_cast<const float4*>(xres + (size_t)b * NE + tid * 4);
  float4 sv = *reinterpret_cast<const float4*>(sres + (size_t)b * NE + tid * 4);
  float s = sv.x + sv.y + sv.z + sv.w;
  float ss = sv.x * sv.x + sv.y * sv.y + sv.z * sv.z + sv.w * sv.w;
  block_red2(s, ss, tmp);
  float m1 = s / NE, rs1 = rsqrtf(ss / NE - m1 * m1 + EPSF);
  float4 sc1 = *reinterpret_cast<const float4*>(lns1 + tid * 4);
  float4 b1 = *reinterpret_cast<const float4*>(lnb1 + tid * 4);
  float4 v;
  v.x = xv.x + (sv.x - m1) * rs1 * sc1.x + b1.x;
  v.y = xv.y + (sv.y - m1) * rs1 * sc1.y + b1.y;
  v.z = xv.z + (sv.z - m1) * rs1 * sc1.z + b1.z;
  v.w = xv.w + (sv.w - m1) * rs1 * sc1.w + b1.w;
  *reinterpret_cast<float4*>(xstore + (size_t)b * NE + tid * 4) = v;
  float s2 = v.x + v.y + v.z + v.w;
  float ss2 = v.x * v.x + v.y * v.y + v.z * v.z + v.w * v.w;
  block_red2(s2, ss2, tmp);
  float m2 = s2 / NE, rs2 = rsqrtf(ss2 / NE - m2 * m2 + EPSF);
  float4 b2 = *reinterpret_cast<const float4*>(lnb2 + tid * 4);
  float4 o;
  o.x = (v.x - m2) * rs2 + b2.x; o.y = (v.y - m2) * rs2 + b2.y;
  o.z = (v.z - m2) * rs2 + b2.z; o.w = (v.w - m2) * rs2 + b2.w;
  *reinterpret_cast<float4*>(hout + (size_t)b * NE + tid * 4) = o;
}

// hout = LN(gelu(gA)*gB) + lnb   (width 4096)
__global__ __launch_bounds__(256) void gelu_ln(const float* __restrict__ gA,
    const float* __restrict__ gB, const float* __restrict__ lnb, float* __restrict__ hout) {
  __shared__ float tmp[8];
  int b = blockIdx.x, tid = threadIdx.x;
  float4 g[4];
  float s = 0.f, ss = 0.f;
#pragma unroll
  for (int q = 0; q < 4; ++q) {
    size_t off = (size_t)b * NG + (tid + 256 * q) * 4;
    float4 a = *reinterpret_cast<const float4*>(gA + off);
    float4 bb = *reinterpret_cast<const float4*>(gB + off);
    float4 gg;
    gg.x = 0.5f * a.x * (1.f + erff(a.x * 0.70710678118f)) * bb.x;
    gg.y = 0.5f * a.y * (1.f + erff(a.y * 0.70710678118f)) * bb.y;
    gg.z = 0.5f * a.z * (1.f + erff(a.z * 0.70710678118f)) * bb.z;
    gg.w = 0.5f * a.w * (1.f + erff(a.w * 0.70710678118f)) * bb.w;
    g[q] = gg;
    s += gg.x + gg.y + gg.z + gg.w;
    ss += gg.x * gg.x + gg.y * gg.y + gg.z * gg.z + gg.w * gg.w;
  }
  block_red2(s, ss, tmp);
  float m = s / NG, rs = rsqrtf(ss / NG - m * m + EPSF);
#pragma unroll
  for (int q = 0; q < 4; ++q) {
    size_t off = (size_t)b * NG + (tid + 256 * q) * 4;
    float4 bi = *reinterpret_cast<const float4*>(lnb + (tid + 256 * q) * 4);
    float4 o;
    o.x = (g[q].x - m) * rs + bi.x; o.y = (g[q].y - m) * rs + bi.y;
    o.z = (g[q].z - m) * rs + bi.z; o.w = (g[q].w - m) * rs + bi.w;
    *reinterpret_cast<float4*>(hout + off) = o;
  }
}

// ---------------- streaming matvec: out[m][8][N] += h[8][k-slice] @ W[m] ----------------
struct MvP {
  const float* W0; const float* W1; const float* W2;
  float* out0; float* out1; float* out2;
  const float* hsrc;   // [8][K] precomputed (LN already applied)
  const float* resid;  // added once (ks==0)
  int K, N, CB, KS;    // BK=K/KS (multiple of 8), block covers 1024 cols
};

__global__ __launch_bounds__(256) void mv_kernel(MvP p) {
  __shared__ float h[8 * 64];
  const int tid = threadIdx.x;
  const int per = p.CB * p.KS;
  const int m = blockIdx.x / per, rem = blockIdx.x % per;
  const int ks = rem / p.CB, cb = rem % p.CB;
  const int BK = p.K / p.KS;
  const int k0 = ks * BK;
  const int n0 = cb * 1024;
  const int bk4 = BK >> 2;
  for (int i = tid; i < 8 * bk4; i += 256) {
    int r = i / bk4, q = i - r * bk4;
    reinterpret_cast<float4*>(h)[i] =
        *reinterpret_cast<const float4*>(p.hsrc + (size_t)r * p.K + k0 + q * 4);
  }
  __syncthreads();

  const int nb = n0 + tid * 4;
  if (nb >= p.N) return;
  const float* W = (m == 0) ? p.W0 : (m == 1) ? p.W1 : p.W2;
  float* out = (m == 0) ? p.out0 : (m == 1) ? p.out1 : p.out2;
  const float* wp = W + (size_t)k0 * p.N + nb;
  const bool addres = (p.resid != nullptr) && (ks == 0);

  if (nb + 3 < p.N) {
    float4 acc[8];
#pragma unroll
    for (int r = 0; r < 8; ++r) acc[r] = make_float4(0.f, 0.f, 0.f, 0.f);
    for (int kk = 0; kk < BK; kk += 8) {
      float4 w[8];
#pragma unroll
      for (int j = 0; j < 8; ++j)
        w[j] = *reinterpret_cast<const float4*>(wp + (size_t)(kk + j) * p.N);
#pragma unroll
      for (int j = 0; j < 8; ++j) {
#pragma unroll
        for (int r = 0; r < 8; ++r) {
          float hv = h[r * BK + kk + j];
          acc[r].x += hv * w[j].x; acc[r].y += hv * w[j].y;
          acc[r].z += hv * w[j].z; acc[r].w += hv * w[j].w;
        }
      }
    }
#pragma unroll
    for (int r = 0; r < 8; ++r) {
      float4 a = acc[r];
      if (addres) {
        const float* rr = p.resid + (size_t)r * p.N + nb;
        a.x += rr[0]; a.y += rr[1]; a.z += rr[2]; a.w += rr[3];
      }
      float* op = out + (size_t)r * p.N + nb;
      atomicAdd(op + 0, a.x); atomicAdd(op + 1, a.y);
      atomicAdd(op + 2, a.z); atomicAdd(op + 3, a.w);
    }
  } else {
    for (int c = 0; c < 4; ++c) {
      if (nb + c >= p.N) break;
      float acc[8] = {0.f, 0.f, 0.f, 0.f, 0.f, 0.f, 0.f, 0.f};
      for (int kk = 0; kk < BK; ++kk) {
        float w = wp[(size_t)kk * p.N + c];
#pragma unroll
        for (int r = 0; r < 8; ++r) acc[r] += h[r * BK + kk] * w;
      }
#pragma unroll
      for (int r = 0; r < 8; ++r) {
        float a = acc[r];
        if (addres) a += p.resid[(size_t)r * p.N + nb + c];
        atomicAdd(out + (size_t)r * p.N + nb + c, a);
      }
    }
  }
}

// ---------------- ast passthrough copy ----------------
__global__ void copy_ast(const float4* __restrict__ in, float4* __restrict__ out, int n4) {
  int i = blockIdx.x * blockDim.x + threadIdx.x;
  int st = gridDim.x * blockDim.x;
  for (; i < n4; i += st) out[i] = in[i];
}

// ---------------- embedding + LN ----------------
__global__ __launch_bounds__(256) void embed_kernel(const float* __restrict__ tok,
    const float* __restrict__ pos, const int* __restrict__ prev, const int* __restrict__ tixp,
    const float* __restrict__ lnb, const float* __restrict__ lns, float* __restrict__ x0) {
  __shared__ float tmp[8];
  int b = blockIdx.x, tid = threadIdx.x;
  const float* te = tok + (size_t)prev[0] * NE;
  const float* pe = pos + (size_t)tixp[0] * NE;
  float4 t4 = *reinterpret_cast<const float4*>(te + tid * 4);
  float4 p4 = *reinterpret_cast<const float4*>(pe + tid * 4);
  float4 v = make_float4(t4.x + p4.x, t4.y + p4.y, t4.z + p4.z, t4.w + p4.w);
  float s = v.x + v.y + v.z + v.w;
  float ss = v.x * v.x + v.y * v.y + v.z * v.z + v.w * v.w;
  block_red2(s, ss, tmp);
  float m = s / NE, rs = rsqrtf(ss / NE - m * m + EPSF);
  float4 sc = *reinterpret_cast<const float4*>(lns + tid * 4);
  float4 bi = *reinterpret_cast<const float4*>(lnb + tid * 4);
  float4 o;
  o.x = (v.x - m) * rs * sc.x + bi.x; o.y = (v.y - m) * rs * sc.y + bi.y;
  o.z = (v.z - m) * rs * sc.z + bi.z; o.w = (v.w - m) * rs * sc.w + bi.w;
  *reinterpret_cast<float4*>(x0 + (size_t)b * NE + tid * 4) = o;
}

// ---------------- self attention + @Wso fused ----------------
__global__ __launch_bounds__(256) void attn_self(const float* __restrict__ q_self,
    const float* __restrict__ kvf, const float* __restrict__ ast, const int* __restrict__ tixp,
    const float* __restrict__ Wso, float* __restrict__ s_self) {
  int b = blockIdx.x >> 4, hh = blockIdx.x & 15;
  int tid = threadIdx.x;
  int tix = tixp[0];
  int T = tix + 1; if (T > NIMG) T = NIMG;
  __shared__ float qv[64];
  __shared__ float sc[256];
  __shared__ float red[256];
  __shared__ float pv[1024];
  __shared__ float ov[64];
  if (tid < 64) qv[tid] = q_self[(size_t)b * NE + hh * 64 + tid] * 0.125f;
  __syncthreads();
  float sj = -INFINITY;
  if (tid < T) {
    const float* kr = (tid == tix) ? (kvf + (size_t)b * NE + hh * 64)
                                   : (ast + ((size_t)b * NIMG + tid) * NE + hh * 64);
    float s = 0.f;
#pragma unroll
    for (int d0 = 0; d0 < 64; d0 += 4) {
      float4 k4 = *reinterpret_cast<const float4*>(kr + d0);
      s += qv[d0] * k4.x + qv[d0 + 1] * k4.y + qv[d0 + 2] * k4.z + qv[d0 + 3] * k4.w;
    }
    sj = s;
  }
  red[tid] = sj; __syncthreads();
  for (int o = 128; o; o >>= 1) { if (tid < o) red[tid] = fmaxf(red[tid], red[tid + o]); __syncthreads(); }
  float mx = red[0]; __syncthreads();
  float e = (tid < T) ? __expf(sj - mx) : 0.f;
  red[tid] = e; __syncthreads();
  for (int o = 128; o; o >>= 1) { if (tid < o) red[tid] += red[tid + o]; __syncthreads(); }
  float inv = 1.f / red[0];
  sc[tid] = e * inv;
  __syncthreads();
  // PV: 16 chunks over kv rows, each thread owns 4 d
  {
    int c = tid >> 4, d4 = (tid & 15) * 4;
    float4 a = make_float4(0.f, 0.f, 0.f, 0.f);
    for (int j = c; j < T; j += 16) {
      const float* vr = (j == tix) ? (kvf + (size_t)(8 + b) * NE + hh * 64)
                                   : (ast + ((size_t)(8 + b) * NIMG + j) * NE + hh * 64);
      float4 v4 = *reinterpret_cast<const float4*>(vr + d4);
      float w = sc[j];
      a.x += w * v4.x; a.y += w * v4.y; a.z += w * v4.z; a.w += w * v4.w;
    }
    pv[c * 64 + d4 + 0] = a.x; pv[c * 64 + d4 + 1] = a.y;
    pv[c * 64 + d4 + 2] = a.z; pv[c * 64 + d4 + 3] = a.w;
  }
  __syncthreads();
  if (tid < 64) {
    float s = 0.f;
#pragma unroll
    for (int c = 0; c < 16; ++c) s += pv[c * 64 + tid];
    ov[tid] = s;
  }
  __syncthreads();
  // s_self[b, nb..] += sum_d ov[d] * Wso[hh*64+d, nb..]
  {
    int nb = tid * 4;
    const float* wp = Wso + (size_t)(hh * 64) * NE + nb;
    float4 acc = make_float4(0.f, 0.f, 0.f, 0.f);
    for (int d = 0; d < 64; d += 8) {
      float4 w[8];
#pragma unroll
      for (int j = 0; j < 8; ++j)
        w[j] = *reinterpret_cast<const float4*>(wp + (size_t)(d + j) * NE);
#pragma unroll
      for (int j = 0; j < 8; ++j) {
        float o = ov[d + j];
        acc.x += o * w[j].x; acc.y += o * w[j].y; acc.z += o * w[j].z; acc.w += o * w[j].w;
      }
    }
    float* op = s_self + (size_t)b * NE + nb;
    atomicAdd(op + 0, acc.x); atomicAdd(op + 1, acc.y);
    atomicAdd(op + 2, acc.z); atomicAdd(op + 3, acc.w);
  }
}

// ---------------- fully fused cross attention: Weq,Wek,scores,softmax,Wev,Weo ----------------
__global__ __launch_bounds__(256) void cross_full(const float* __restrict__ h2,
    const float* __restrict__ Weq, const float* __restrict__ Wek, const float* __restrict__ Wev,
    const float* __restrict__ Weo, const float* __restrict__ X, const void* __restrict__ maskp,
    float* __restrict__ s_enc) {
  int b = blockIdx.x >> 4, hh = blockIdx.x & 15;
  int tid = threadIdx.x;
  __shared__ float vecA[NE];   // h2 row, later wX
  __shared__ float vecB[NE];   // partials, later qW, later partials
  __shared__ float red[256];
  __shared__ float w_[NTT];
  __shared__ float qv[64];
  __shared__ float oe[64];
  __shared__ int mask_i32;
  if (tid == 0) {
    const unsigned int* w = (const unsigned int*)maskp;
    int i32 = 1;
    for (int j = 0; j < 128; ++j) { if (w[j] > 1u) { i32 = 0; break; } }
    mask_i32 = i32;
  }
  reinterpret_cast<float4*>(vecA)[tid] =
      *reinterpret_cast<const float4*>(h2 + (size_t)b * NE + tid * 4);
  __syncthreads();

  // qe[d] = sum_e h2[e] * Weq[e, hh*64+d]
  {
    int d4 = (tid & 15) * 4, ech = tid >> 4;
    const float* base = Weq + hh * 64 + d4;
    float4 a = make_float4(0.f, 0.f, 0.f, 0.f);
    for (int e = ech * 64; e < ech * 64 + 64; e += 8) {
      float4 w[8];
#pragma unroll
      for (int j = 0; j < 8; ++j)
        w[j] = *reinterpret_cast<const float4*>(base + (size_t)(e + j) * NE);
#pragma unroll
      for (int j = 0; j < 8; ++j) {
        float hv = vecA[e + j];
        a.x += hv * w[j].x; a.y += hv * w[j].y; a.z += hv * w[j].z; a.w += hv * w[j].w;
      }
    }
    vecB[ech * 64 + d4 + 0] = a.x; vecB[ech * 64 + d4 + 1] = a.y;
    vecB[ech * 64 + d4 + 2] = a.z; vecB[ech * 64 + d4 + 3] = a.w;
  }
  __syncthreads();
  if (tid < 64) {
    float s = 0.f;
#pragma unroll
    for (int c = 0; c < 16; ++c) s += vecB[c * 64 + tid];
    qv[tid] = s;
  }
  __syncthreads();

  // qW[e] = sum_d qv[d] * Wek[e, hh*64+d]
  {
    float qwtmp[4];
#pragma unroll
    for (int jj = 0; jj < 4; ++jj) {
      int e = tid + 256 * jj;
      const float* wr = Wek + (size_t)e * NE + hh * 64;
      float a = 0.f;
#pragma unroll
      for (int d0 = 0; d0 < 64; d0 += 4) {
        float4 w4 = *reinterpret_cast<const float4*>(wr + d0);
        a += qv[d0] * w4.x + qv[d0 + 1] * w4.y + qv[d0 + 2] * w4.z + qv[d0 + 3] * w4.w;
      }
      qwtmp[jj] = a;
    }
#pragma unroll
    for (int jj = 0; jj < 4; ++jj) vecB[tid + 256 * jj] = qwtmp[jj];
  }
  __syncthreads();

  // scores[t] = 0.125 * sum_e qW[e] X[b,t,e] ; mask ; softmax
  {
    int t = tid & 63, ec = tid >> 6;
    const float* xr = X + ((size_t)b * NTT + t) * NE + ec * 256;
    float part = 0.f;
#pragma unroll 4
    for (int i = 0; i < 256; i += 4) {
      float4 x4 = *reinterpret_cast<const float4*>(xr + i);
      part += vecB[ec * 256 + i] * x4.x + vecB[ec * 256 + i + 1] * x4.y +
              vecB[ec * 256 + i + 2] * x4.z + vecB[ec * 256 + i + 3] * x4.w;
    }
    red[ec * 64 + t] = part;
  }
  __syncthreads();
  float sco = -INFINITY;
  if (tid < 64) {
    float s = (red[tid] + red[64 + tid] + red[128 + tid] + red[192 + tid]) * 0.125f;
    int idx = b * NTT + tid;
    bool valid = mask_i32 ? (((const int*)maskp)[idx] != 0)
                          : (((const unsigned char*)maskp)[idx] != 0);
    sco = valid ? s : -INFINITY;
  }
  __syncthreads();
  red[tid] = (tid < 64) ? sco : -INFINITY; __syncthreads();
  for (int o = 128; o; o >>= 1) { if (tid < o) red[tid] = fmaxf(red[tid], red[tid + o]); __syncthreads(); }
  float mx = red[0]; __syncthreads();
  float e = (tid < 64) ? __expf(sco - mx) : 0.f;
  red[tid] = e; __syncthreads();
  for (int o = 128; o; o >>= 1) { if (tid < o) red[tid] += red[tid + o]; __syncthreads(); }
  if (tid < 64) w_[tid] = e / red[0];
  __syncthreads();

  // wX[e] = sum_t w_[t] * X[b,t,e]
  {
    float4 a = make_float4(0.f, 0.f, 0.f, 0.f);
    const float* xb = X + (size_t)b * NTT * NE + tid * 4;
    for (int t = 0; t < NTT; t += 4) {
#pragma unroll
      for (int j = 0; j < 4; ++j) {
        float4 x4 = *reinterpret_cast<const float4*>(xb + (size_t)(t + j) * NE);
        float w = w_[t + j];
        a.x += w * x4.x; a.y += w * x4.y; a.z += w * x4.z; a.w += w * x4.w;
      }
    }
    reinterpret_cast<float4*>(vecA)[tid] = a;
  }
  __syncthreads();

  // oe[d] = sum_e wX[e] * Wev[e, hh*64+d]
  {
    int d4 = (tid & 15) * 4, ech = tid >> 4;
    const float* base = Wev + hh * 64 + d4;
    float4 a = make_float4(0.f, 0.f, 0.f, 0.f);
    for (int e = ech * 64; e < ech * 64 + 64; e += 8) {
      float4 w[8];
#pragma unroll
      for (int j = 0; j < 8; ++j)
        w[j] = *reinterpret_cast<const float4*>(base + (size_t)(e + j) * NE);
#pragma unroll
      for (int j = 0; j < 8; ++j) {
        float hv = vecA[e + j];
        a.x += hv * w[j].x; a.y += hv * w[j].y; a.z += hv * w[j].z; a.w += hv * w[j].w;
      }
    }
    vecB[ech * 64 + d4 + 0] = a.x; vecB[ech * 64 + d4 + 1] = a.y;
    vecB[ech * 64 + d4 + 2] = a.z; vecB[ech * 64 + d4 + 3] = a.w;
  }
  __syncthreads();
  if (tid < 64) {
    float s = 0.f;
#pragma unroll
    for (int c = 0; c < 16; ++c) s += vecB[c * 64 + tid];
    oe[tid] = s;
  }
  __syncthreads();

  // s_enc[b, nb..] += sum_d oe[d] * Weo[hh*64+d, nb..]
  {
    int nb = tid * 4;
    const float* wp = Weo + (size_t)(hh * 64) * NE + nb;
    float4 acc = make_float4(0.f, 0.f, 0.f, 0.f);
    for (int d = 0; d < 64; d += 8) {
      float4 w[8];
#pragma unroll
      for (int j = 0; j < 8; ++j)
        w[j] = *reinterpret_cast<const float4*>(wp + (size_t)(d + j) * NE);
#pragma unroll
      for (int j = 0; j < 8; ++j) {
        float o = oe[d + j];
        acc.x += o * w[j].x; acc.y += o * w[j].y; acc.z += o * w[j].z; acc.w += o * w[j].w;
      }
    }
    float* op = s_enc + (size_t)b * NE + nb;
    atomicAdd(op + 0, acc.x); atomicAdd(op + 1, acc.y);
    atomicAdd(op + 2, acc.z); atomicAdd(op + 3, acc.w);
  }
}

// ---------------- write fresh k,v rows into output attention_state ----------------
__global__ void kv_out_kernel(const float* __restrict__ kv, float* __restrict__ out_ast,
                              const int* __restrict__ tixp) {
  int l = blockIdx.x >> 4, r = blockIdx.x & 15;
  int tix = tixp[0];
  const float* src = kv + (size_t)(l * 16 + r) * NE;
  float* dst = out_ast + (((size_t)(l * 16 + r)) * NIMG + tix) * NE;
  for (int i = threadIdx.x; i < NE; i += 256) dst[i] = src[i];
}

extern "C" void kernel_launch(void* const* d_in, const int* in_sizes, int n_in,
                              void* d_out, int out_size, void* d_ws, size_t ws_size,
                              hipStream_t stream) {
  const float* enc_state = (const float*)d_in[0];
  const float* ast_in    = (const float*)d_in[1];
  const void* amask      = d_in[2];
  const int* prev = (const int*)d_in[3];
  const int* tix  = (const int*)d_in[4];
  const float* embed_tok = (const float*)d_in[5];
  const float* embed_pos = (const float*)d_in[6];
  const float* lnemb_s = (const float*)d_in[7];
  const float* lnemb_b = (const float*)d_in[8];
  const float* psb = (const float*)d_in[9];
  const float* Wsq = (const float*)d_in[10];
  const float* Wsk = (const float*)d_in[11];
  const float* Wsv = (const float*)d_in[12];
  const float* Wso = (const float*)d_in[13];
  const float* sls = (const float*)d_in[14];
  const float* slb = (const float*)d_in[15];
  const float* peb = (const float*)d_in[16];
  const float* Weq = (const float*)d_in[17];
  const float* Wek = (const float*)d_in[18];
  const float* Wev = (const float*)d_in[19];
  const float* Weo = (const float*)d_in[20];
  const float* els = (const float*)d_in[21];
  const float* elb = (const float*)d_in[22];
  const float* g0b = (const float*)d_in[23];
  const float* Wf0 = (const float*)d_in[24];
  const float* Wf1 = (const float*)d_in[25];
  const float* g1b = (const float*)d_in[26];
  const float* Wf2 = (const float*)d_in[27];
  const float* flb = (const float*)d_in[28];
  const float* Wlm = (const float*)d_in[29];

  float* ws = (float*)d_ws;
  float* logits = (float*)d_out;
  float* out_ast = logits + (size_t)NB * NV;

  hipMemsetAsync(d_ws, 0, (size_t)AEND * sizeof(float), stream);
  hipMemsetAsync(d_out, 0, (size_t)NB * NV * sizeof(float), stream);

  copy_ast<<<4096, 256, 0, stream>>>((const float4*)ast_in, (float4*)out_ast,
                                     NL * 16 * NIMG * NE / 4);
  embed_kernel<<<NB, 256, 0, stream>>>(embed_tok, embed_pos, prev, tix, lnemb_b, lnemb_s,
                                       ws + DX0);

  for (int l = 0; l < NL; ++l) {
    float* xl  = (l == 0) ? (ws + DX0) : (ws + AX + (size_t)(l - 1) * 8192);
    float* xn  = ws + AX + (size_t)l * 8192;
    float* kvl = ws + AKV + (size_t)l * 16384;
    float* qsl = ws + AQS + (size_t)l * 8192;
    float* ssl = ws + ASS + (size_t)l * 8192;
    float* sel = ws + ASE + (size_t)l * 8192;
    float* gal = ws + AGA + (size_t)l * 32768;
    float* gbl = ws + AGB + (size_t)l * 32768;
    size_t wE = (size_t)l * NE * NE;
    size_t wG = (size_t)l * NE * NG;

    // h1 = LN(x, psb)
    ln_simple<<<NB, 256, 0, stream>>>(xl, nullptr, psb + (size_t)l * NE, ws + DH1);
    {  // k,v,q = h1 @ {Wsk,Wsv,Wsq}
      MvP p{}; p.W0 = Wsk + wE; p.W1 = Wsv + wE; p.W2 = Wsq + wE;
      p.out0 = kvl; p.out1 = kvl + 8 * NE; p.out2 = qsl;
      p.hsrc = ws + DH1; p.K = NE; p.N = NE; p.CB = 1; p.KS = 32;
      mv_kernel<<<3 * 32, 256, 0, stream>>>(p);
    }
    attn_self<<<NB * NH, 256, 0, stream>>>(qsl, kvl, ast_in + (size_t)l * 16 * NIMG * NE,
                                           tix, Wso + wE, ssl);
    // x2 = x + LN(s_self, sls, slb); h2 = LN(x2, peb)
    ln_res<<<NB, 256, 0, stream>>>(xl, ssl, sls + (size_t)l * NE, slb + (size_t)l * NE,
                                   peb + (size_t)l * NE, ws + DX2, ws + DH2);
    cross_full<<<NB * NH, 256, 0, stream>>>(ws + DH2, Weq + wE, Wek + wE, Wev + wE,
                                            Weo + wE, enc_state, amask, sel);
    // x3 = x2 + LN(s_enc, els, elb); h3 = LN(x3, g0b)
    ln_res<<<NB, 256, 0, stream>>>(ws + DX2, sel, els + (size_t)l * NE, elb + (size_t)l * NE,
                                   g0b + (size_t)l * NE, ws + DX3, ws + DH3);
    {  // gA = h3@fc0, gB = h3@fc1
      MvP p{}; p.W0 = Wf0 + wG; p.W1 = Wf1 + wG;
      p.out0 = gal; p.out1 = gbl;
      p.hsrc = ws + DH3; p.K = NE; p.N = NG; p.CB = 4; p.KS = 32;
      mv_kernel<<<2 * 4 * 32, 256, 0, stream>>>(p);
    }
    // hg = LN(gelu(gA)*gB, g1b)
    gelu_ln<<<NB, 256, 0, stream>>>(gal, gbl, g1b + (size_t)l * NG, ws + DHG);
    {  // x_{l+1} = x3 + hg @ fc2
      MvP p{}; p.W0 = Wf2 + (size_t)l * NG * NE; p.out0 = xn;
      p.hsrc = ws + DHG; p.resid = ws + DX3;
      p.K = NG; p.N = NE; p.CB = 1; p.KS = 64;
      mv_kernel<<<64, 256, 0, stream>>>(p);
    }
  }
  // hf = LN(x4, final_ln_b); logits = hf @ lm_head
  ln_simple<<<NB, 256, 0, stream>>>(ws + AX + 3 * 8192, nullptr, flb, ws + DHF);
  {
    MvP p{}; p.W0 = Wlm; p.out0 = logits; p.hsrc = ws + DHF;
    p.K = NE; p.N = NV; p.CB = 17; p.KS = 32;
    mv_kernel<<<17 * 32, 256, 0, stream>>>(p);
  }
  kv_out_kernel<<<NL * 16, 256, 0, stream>>>(ws + AKV, out_ast, tix);
}

// Round 5
// 613.047 us; speedup vs baseline: 2.3567x; 1.2465x over previous
//
#include <hip/hip_runtime.h>
#include <math.h>

#define EPSF 1e-6f

#define NL 4
#define NB 8
#define NE 1024
#define NH 16
#define NG 4096
#define NIMG 256
#define NTT 64
#define NV 16385
#define NVPAD 17408

// ---- workspace float offsets (no zeroing needed; all plain stores) ----
#define P_QKV   0          // [3][32][8][1024]  = 786432
#define P_FC01  786432     // [2][16][8][4096]  = 1048576
#define P_FC2   1835008    // [64][8][1024]     = 524288
#define P_LM    2359296    // [16][8][17408]    = 2228224
#define QSELF   4587520    // [8][1024]
#define KVBUF   4595712    // [16][1024]
#define SSPART  4612096    // [16][8][1024]
#define SEPART  4743168    // [16][8][1024]
#define XBUF    4874240    // [8][1024]
#define DH1     4882432
#define DX2     4890624
#define DH2     4898816
#define DX3     4907008
#define DH3     4915200
#define DHG     4923392    // [8][4096]
#define DHF     4956160

__device__ inline void wave_red2(float& a, float& b) {
#pragma unroll
  for (int o = 32; o; o >>= 1) { a += __shfl_xor(a, o); b += __shfl_xor(b, o); }
}

__device__ inline void block_red2(float& s, float& ss, float* tmp) {
  wave_red2(s, ss);
  int wv = threadIdx.x >> 6, ln = threadIdx.x & 63;
  if (ln == 0) { tmp[wv] = s; tmp[4 + wv] = ss; }
  __syncthreads();
  s = tmp[0] + tmp[1] + tmp[2] + tmp[3];
  ss = tmp[4] + tmp[5] + tmp[6] + tmp[7];
  __syncthreads();
}

__device__ inline float4 f4add(float4 a, float4 b) {
  return make_float4(a.x + b.x, a.y + b.y, a.z + b.z, a.w + b.w);
}

// ---------------- streaming matvec to K-split partials (no atomics) ----------------
// partial[mat][ks][8][NPAD] = h[8][k-slice] @ W[mat][k-slice]
struct MvPartP {
  const float* W0; const float* W1; const float* W2;
  float* pout;
  const float* hsrc;   // [8][K], LN already applied
  int K, N, NPAD, CB, KS;  // BK=K/KS multiple of 8; block covers 1024 cols
};

__global__ __launch_bounds__(256) void mv_part(MvPartP p) {
  __shared__ float h[8 * 64];
  const int tid = threadIdx.x;
  const int per = p.CB * p.KS;
  const int m = blockIdx.x / per, rem = blockIdx.x % per;
  const int ks = rem / p.CB, cb = rem % p.CB;
  const int BK = p.K / p.KS;
  const int k0 = ks * BK;
  const int n0 = cb * 1024;
  const int bk4 = BK >> 2;
  for (int i = tid; i < 8 * bk4; i += 256) {
    int r = i / bk4, q = i - r * bk4;
    reinterpret_cast<float4*>(h)[i] =
        *reinterpret_cast<const float4*>(p.hsrc + (size_t)r * p.K + k0 + q * 4);
  }
  __syncthreads();

  const int nb = n0 + tid * 4;
  if (nb >= p.N) return;
  const float* W = (m == 0) ? p.W0 : (m == 1) ? p.W1 : p.W2;
  float* pr = p.pout + (size_t)(m * p.KS + ks) * 8 * p.NPAD;
  const float* wp = W + (size_t)k0 * p.N + nb;

  if (nb + 3 < p.N) {
    float4 acc[8];
#pragma unroll
    for (int r = 0; r < 8; ++r) acc[r] = make_float4(0.f, 0.f, 0.f, 0.f);
    for (int kk = 0; kk < BK; kk += 8) {
      float4 w[8];
#pragma unroll
      for (int j = 0; j < 8; ++j)
        w[j] = *reinterpret_cast<const float4*>(wp + (size_t)(kk + j) * p.N);
#pragma unroll
      for (int j = 0; j < 8; ++j) {
#pragma unroll
        for (int r = 0; r < 8; ++r) {
          float hv = h[r * BK + kk + j];
          acc[r].x += hv * w[j].x; acc[r].y += hv * w[j].y;
          acc[r].z += hv * w[j].z; acc[r].w += hv * w[j].w;
        }
      }
    }
#pragma unroll
    for (int r = 0; r < 8; ++r)
      *reinterpret_cast<float4*>(pr + (size_t)r * p.NPAD + nb) = acc[r];
  } else {
    for (int c = 0; c < 4; ++c) {
      if (nb + c >= p.N) break;
      float acc[8] = {0.f, 0.f, 0.f, 0.f, 0.f, 0.f, 0.f, 0.f};
      for (int kk = 0; kk < BK; ++kk) {
        float w = wp[(size_t)kk * p.N + c];
#pragma unroll
        for (int r = 0; r < 8; ++r) acc[r] += h[r * BK + kk] * w;
      }
#pragma unroll
      for (int r = 0; r < 8; ++r) pr[(size_t)r * p.NPAD + nb + c] = acc[r];
    }
  }
}

// ---------------- reduce qkv partials; also write fresh k,v into out_ast ----------------
__global__ __launch_bounds__(256) void reduce_qkv(const float* __restrict__ P,
    float* __restrict__ q_self, float* __restrict__ kv, float* __restrict__ out_ast_l,
    const int* __restrict__ tixp) {
  int m = blockIdx.x >> 3, r = blockIdx.x & 7;
  int col = threadIdx.x * 4;
  const float* base = P + ((size_t)(m * 32) * 8 + r) * 1024 + col;
  float4 acc = make_float4(0.f, 0.f, 0.f, 0.f);
  for (int ks = 0; ks < 32; ks += 8) {
    float4 w[8];
#pragma unroll
    for (int j = 0; j < 8; ++j)
      w[j] = *reinterpret_cast<const float4*>(base + (size_t)(ks + j) * 8192);
#pragma unroll
    for (int j = 0; j < 8; ++j) acc = f4add(acc, w[j]);
  }
  if (m == 2) {
    *reinterpret_cast<float4*>(q_self + (size_t)r * 1024 + col) = acc;
  } else {
    int row = (m == 0) ? r : 8 + r;
    *reinterpret_cast<float4*>(kv + (size_t)row * 1024 + col) = acc;
    int tix = tixp[0];
    if (tix < NIMG)
      *reinterpret_cast<float4*>(out_ast_l + ((size_t)row * NIMG + tix) * 1024 + col) = acc;
  }
}

// ---------------- ast passthrough copy ----------------
__global__ void copy_ast(const float4* __restrict__ in, float4* __restrict__ out, int n4) {
  int i = blockIdx.x * blockDim.x + threadIdx.x;
  int st = gridDim.x * blockDim.x;
  for (; i < n4; i += st) out[i] = in[i];
}

// ---------------- embedding + LN(lnemb) -> x0 ; LN(x0)+psb0 -> h1 ----------------
__global__ __launch_bounds__(256) void embed_kernel(const float* __restrict__ tok,
    const float* __restrict__ pos, const int* __restrict__ prev, const int* __restrict__ tixp,
    const float* __restrict__ lnb, const float* __restrict__ lns,
    const float* __restrict__ psb0, float* __restrict__ x0, float* __restrict__ h1) {
  __shared__ float tmp[8];
  int b = blockIdx.x, tid = threadIdx.x;
  const float* te = tok + (size_t)prev[0] * NE;
  const float* pe = pos + (size_t)tixp[0] * NE;
  float4 t4 = *reinterpret_cast<const float4*>(te + tid * 4);
  float4 p4 = *reinterpret_cast<const float4*>(pe + tid * 4);
  float4 v = make_float4(t4.x + p4.x, t4.y + p4.y, t4.z + p4.z, t4.w + p4.w);
  float s = v.x + v.y + v.z + v.w;
  float ss = v.x * v.x + v.y * v.y + v.z * v.z + v.w * v.w;
  block_red2(s, ss, tmp);
  float m = s / NE, rs = rsqrtf(ss / NE - m * m + EPSF);
  float4 sc = *reinterpret_cast<const float4*>(lns + tid * 4);
  float4 bi = *reinterpret_cast<const float4*>(lnb + tid * 4);
  float4 x;
  x.x = (v.x - m) * rs * sc.x + bi.x; x.y = (v.y - m) * rs * sc.y + bi.y;
  x.z = (v.z - m) * rs * sc.z + bi.z; x.w = (v.w - m) * rs * sc.w + bi.w;
  *reinterpret_cast<float4*>(x0 + (size_t)b * NE + tid * 4) = x;
  float s2 = x.x + x.y + x.z + x.w;
  float ss2 = x.x * x.x + x.y * x.y + x.z * x.z + x.w * x.w;
  block_red2(s2, ss2, tmp);
  float m2 = s2 / NE, rs2 = rsqrtf(ss2 / NE - m2 * m2 + EPSF);
  float4 b2 = *reinterpret_cast<const float4*>(psb0 + tid * 4);
  float4 o;
  o.x = (x.x - m2) * rs2 + b2.x; o.y = (x.y - m2) * rs2 + b2.y;
  o.z = (x.z - m2) * rs2 + b2.z; o.w = (x.w - m2) * rs2 + b2.w;
  *reinterpret_cast<float4*>(h1 + (size_t)b * NE + tid * 4) = o;
}

// ---------------- x_next = resid + sum_ks fc2part ; h = LN(x_next)+bias ----------------
__global__ __launch_bounds__(256) void ln_fc2(const float* __restrict__ P,
    const float* __restrict__ resid, const float* __restrict__ bias,
    float* __restrict__ xout, float* __restrict__ hout, int KS) {
  __shared__ float tmp[8];
  int b = blockIdx.x, tid = threadIdx.x;
  int col = tid * 4;
  float4 acc = *reinterpret_cast<const float4*>(resid + (size_t)b * NE + col);
  const float* base = P + (size_t)b * 1024 + col;
  for (int ks = 0; ks < KS; ks += 8) {
    float4 w[8];
#pragma unroll
    for (int j = 0; j < 8; ++j)
      w[j] = *reinterpret_cast<const float4*>(base + (size_t)(ks + j) * 8192);
#pragma unroll
    for (int j = 0; j < 8; ++j) acc = f4add(acc, w[j]);
  }
  *reinterpret_cast<float4*>(xout + (size_t)b * NE + col) = acc;
  float s = acc.x + acc.y + acc.z + acc.w;
  float ss = acc.x * acc.x + acc.y * acc.y + acc.z * acc.z + acc.w * acc.w;
  block_red2(s, ss, tmp);
  float m = s / NE, rs = rsqrtf(ss / NE - m * m + EPSF);
  float4 bi = *reinterpret_cast<const float4*>(bias + col);
  float4 o;
  o.x = (acc.x - m) * rs + bi.x; o.y = (acc.y - m) * rs + bi.y;
  o.z = (acc.z - m) * rs + bi.z; o.w = (acc.w - m) * rs + bi.w;
  *reinterpret_cast<float4*>(hout + (size_t)b * NE + col) = o;
}

// ---------------- x2 = x + LN(sum_h part; lns1,lnb1); h = LN(x2)+lnb2 ----------------
__global__ __launch_bounds__(256) void ln_res_sum(const float* __restrict__ xres,
    const float* __restrict__ part, const float* __restrict__ lns1,
    const float* __restrict__ lnb1, const float* __restrict__ lnb2,
    float* __restrict__ xstore, float* __restrict__ hout) {
  __shared__ float tmp[8];
  int b = blockIdx.x, tid = threadIdx.x;
  int col = tid * 4;
  float4 sv = make_float4(0.f, 0.f, 0.f, 0.f);
  const float* base = part + (size_t)b * 1024 + col;
#pragma unroll
  for (int h = 0; h < 16; h += 8) {
    float4 w[8];
#pragma unroll
    for (int j = 0; j < 8; ++j)
      w[j] = *reinterpret_cast<const float4*>(base + (size_t)(h + j) * 8192);
#pragma unroll
    for (int j = 0; j < 8; ++j) sv = f4add(sv, w[j]);
  }
  float s = sv.x + sv.y + sv.z + sv.w;
  float ss = sv.x * sv.x + sv.y * sv.y + sv.z * sv.z + sv.w * sv.w;
  block_red2(s, ss, tmp);
  float m1 = s / NE, rs1 = rsqrtf(ss / NE - m1 * m1 + EPSF);
  float4 xv = *reinterpret_cast<const float4*>(xres + (size_t)b * NE + col);
  float4 sc1 = *reinterpret_cast<const float4*>(lns1 + col);
  float4 b1 = *reinterpret_cast<const float4*>(lnb1 + col);
  float4 v;
  v.x = xv.x + (sv.x - m1) * rs1 * sc1.x + b1.x;
  v.y = xv.y + (sv.y - m1) * rs1 * sc1.y + b1.y;
  v.z = xv.z + (sv.z - m1) * rs1 * sc1.z + b1.z;
  v.w = xv.w + (sv.w - m1) * rs1 * sc1.w + b1.w;
  *reinterpret_cast<float4*>(xstore + (size_t)b * NE + col) = v;
  float s2 = v.x + v.y + v.z + v.w;
  float ss2 = v.x * v.x + v.y * v.y + v.z * v.z + v.w * v.w;
  block_red2(s2, ss2, tmp);
  float m2 = s2 / NE, rs2 = rsqrtf(ss2 / NE - m2 * m2 + EPSF);
  float4 b2 = *reinterpret_cast<const float4*>(lnb2 + col);
  float4 o;
  o.x = (v.x - m2) * rs2 + b2.x; o.y = (v.y - m2) * rs2 + b2.y;
  o.z = (v.z - m2) * rs2 + b2.z; o.w = (v.w - m2) * rs2 + b2.w;
  *reinterpret_cast<float4*>(hout + (size_t)b * NE + col) = o;
}

// ---------------- hg = LN(gelu(sumA)*sumB)+lnb (width 4096) ----------------
__global__ __launch_bounds__(256) void gelu_ln_sum(const float* __restrict__ P,
    const float* __restrict__ lnb, float* __restrict__ hout) {
  __shared__ float tmp[8];
  int b = blockIdx.x, tid = threadIdx.x;
  float4 g[4];
  float s = 0.f, ss = 0.f;
#pragma unroll
  for (int q = 0; q < 4; ++q) {
    int col = (tid + 256 * q) * 4;
    float4 a = make_float4(0.f, 0.f, 0.f, 0.f);
    float4 bb = make_float4(0.f, 0.f, 0.f, 0.f);
    const float* baseA = P + (size_t)b * 4096 + col;
    const float* baseB = P + ((size_t)16 * 8 + b) * 4096 + col;
#pragma unroll
    for (int ks = 0; ks < 16; ++ks) {
      a = f4add(a, *reinterpret_cast<const float4*>(baseA + (size_t)ks * 32768));
      bb = f4add(bb, *reinterpret_cast<const float4*>(baseB + (size_t)ks * 32768));
    }
    float4 gg;
    gg.x = 0.5f * a.x * (1.f + erff(a.x * 0.70710678118f)) * bb.x;
    gg.y = 0.5f * a.y * (1.f + erff(a.y * 0.70710678118f)) * bb.y;
    gg.z = 0.5f * a.z * (1.f + erff(a.z * 0.70710678118f)) * bb.z;
    gg.w = 0.5f * a.w * (1.f + erff(a.w * 0.70710678118f)) * bb.w;
    g[q] = gg;
    s += gg.x + gg.y + gg.z + gg.w;
    ss += gg.x * gg.x + gg.y * gg.y + gg.z * gg.z + gg.w * gg.w;
  }
  block_red2(s, ss, tmp);
  float m = s / NG, rs = rsqrtf(ss / NG - m * m + EPSF);
#pragma unroll
  for (int q = 0; q < 4; ++q) {
    int col = (tid + 256 * q) * 4;
    float4 bi = *reinterpret_cast<const float4*>(lnb + col);
    float4 o;
    o.x = (g[q].x - m) * rs + bi.x; o.y = (g[q].y - m) * rs + bi.y;
    o.z = (g[q].z - m) * rs + bi.z; o.w = (g[q].w - m) * rs + bi.w;
    *reinterpret_cast<float4*>(hout + (size_t)b * NG + col) = o;
  }
}

// ---------------- self attention + @Wso, per-head partial store ----------------
__global__ __launch_bounds__(256) void attn_self(const float* __restrict__ q_self,
    const float* __restrict__ kvf, const float* __restrict__ ast, const int* __restrict__ tixp,
    const float* __restrict__ Wso, float* __restrict__ spart) {
  int b = blockIdx.x >> 4, hh = blockIdx.x & 15;
  int tid = threadIdx.x;
  int tix = tixp[0];
  int T = tix + 1; if (T > NIMG) T = NIMG;
  __shared__ float qv[64];
  __shared__ float sc[256];
  __shared__ float red[256];
  __shared__ float pv[1024];
  __shared__ float ov[64];
  if (tid < 64) qv[tid] = q_self[(size_t)b * NE + hh * 64 + tid] * 0.125f;
  __syncthreads();
  float sj = -INFINITY;
  if (tid < T) {
    const float* kr = (tid == tix) ? (kvf + (size_t)b * NE + hh * 64)
                                   : (ast + ((size_t)b * NIMG + tid) * NE + hh * 64);
    float s = 0.f;
#pragma unroll
    for (int d0 = 0; d0 < 64; d0 += 4) {
      float4 k4 = *reinterpret_cast<const float4*>(kr + d0);
      s += qv[d0] * k4.x + qv[d0 + 1] * k4.y + qv[d0 + 2] * k4.z + qv[d0 + 3] * k4.w;
    }
    sj = s;
  }
  red[tid] = sj; __syncthreads();
  for (int o = 128; o; o >>= 1) { if (tid < o) red[tid] = fmaxf(red[tid], red[tid + o]); __syncthreads(); }
  float mx = red[0]; __syncthreads();
  float e = (tid < T) ? __expf(sj - mx) : 0.f;
  red[tid] = e; __syncthreads();
  for (int o = 128; o; o >>= 1) { if (tid < o) red[tid] += red[tid + o]; __syncthreads(); }
  float inv = 1.f / red[0];
  sc[tid] = e * inv;
  __syncthreads();
  {
    int c = tid >> 4, d4 = (tid & 15) * 4;
    float4 a = make_float4(0.f, 0.f, 0.f, 0.f);
    for (int j = c; j < T; j += 16) {
      const float* vr = (j == tix) ? (kvf + (size_t)(8 + b) * NE + hh * 64)
                                   : (ast + ((size_t)(8 + b) * NIMG + j) * NE + hh * 64);
      float4 v4 = *reinterpret_cast<const float4*>(vr + d4);
      float w = sc[j];
      a.x += w * v4.x; a.y += w * v4.y; a.z += w * v4.z; a.w += w * v4.w;
    }
    pv[c * 64 + d4 + 0] = a.x; pv[c * 64 + d4 + 1] = a.y;
    pv[c * 64 + d4 + 2] = a.z; pv[c * 64 + d4 + 3] = a.w;
  }
  __syncthreads();
  if (tid < 64) {
    float s = 0.f;
#pragma unroll
    for (int c = 0; c < 16; ++c) s += pv[c * 64 + tid];
    ov[tid] = s;
  }
  __syncthreads();
  {
    int nb = tid * 4;
    const float* wp = Wso + (size_t)(hh * 64) * NE + nb;
    float4 acc = make_float4(0.f, 0.f, 0.f, 0.f);
    for (int d = 0; d < 64; d += 8) {
      float4 w[8];
#pragma unroll
      for (int j = 0; j < 8; ++j)
        w[j] = *reinterpret_cast<const float4*>(wp + (size_t)(d + j) * NE);
#pragma unroll
      for (int j = 0; j < 8; ++j) {
        float o = ov[d + j];
        acc.x += o * w[j].x; acc.y += o * w[j].y; acc.z += o * w[j].z; acc.w += o * w[j].w;
      }
    }
    *reinterpret_cast<float4*>(spart + ((size_t)hh * 8 + b) * 1024 + nb) = acc;
  }
}

// ---------------- fused cross attention, per-head partial store ----------------
__global__ __launch_bounds__(256) void cross_full(const float* __restrict__ h2,
    const float* __restrict__ Weq, const float* __restrict__ Wek, const float* __restrict__ Wev,
    const float* __restrict__ Weo, const float* __restrict__ X, const void* __restrict__ maskp,
    float* __restrict__ spart) {
  int b = blockIdx.x >> 4, hh = blockIdx.x & 15;
  int tid = threadIdx.x;
  __shared__ float vecA[NE];
  __shared__ float vecB[NE];
  __shared__ float red[256];
  __shared__ float w_[NTT];
  __shared__ float qv[64];
  __shared__ float oe[64];
  __shared__ int mask_i32;
  if (tid == 0) {
    const unsigned int* w = (const unsigned int*)maskp;
    int i32 = 1;
    for (int j = 0; j < 128; ++j) { if (w[j] > 1u) { i32 = 0; break; } }
    mask_i32 = i32;
  }
  reinterpret_cast<float4*>(vecA)[tid] =
      *reinterpret_cast<const float4*>(h2 + (size_t)b * NE + tid * 4);
  __syncthreads();

  {  // qe[d] = sum_e h2[e] * Weq[e, hh*64+d]
    int d4 = (tid & 15) * 4, ech = tid >> 4;
    const float* base = Weq + hh * 64 + d4;
    float4 a = make_float4(0.f, 0.f, 0.f, 0.f);
    for (int e = ech * 64; e < ech * 64 + 64; e += 8) {
      float4 w[8];
#pragma unroll
      for (int j = 0; j < 8; ++j)
        w[j] = *reinterpret_cast<const float4*>(base + (size_t)(e + j) * NE);
#pragma unroll
      for (int j = 0; j < 8; ++j) {
        float hv = vecA[e + j];
        a.x += hv * w[j].x; a.y += hv * w[j].y; a.z += hv * w[j].z; a.w += hv * w[j].w;
      }
    }
    vecB[ech * 64 + d4 + 0] = a.x; vecB[ech * 64 + d4 + 1] = a.y;
    vecB[ech * 64 + d4 + 2] = a.z; vecB[ech * 64 + d4 + 3] = a.w;
  }
  __syncthreads();
  if (tid < 64) {
    float s = 0.f;
#pragma unroll
    for (int c = 0; c < 16; ++c) s += vecB[c * 64 + tid];
    qv[tid] = s;
  }
  __syncthreads();

  {  // qW[e] = sum_d qv[d] * Wek[e, hh*64+d]
    float qwtmp[4];
#pragma unroll
    for (int jj = 0; jj < 4; ++jj) {
      int e = tid + 256 * jj;
      const float* wr = Wek + (size_t)e * NE + hh * 64;
      float a = 0.f;
#pragma unroll
      for (int d0 = 0; d0 < 64; d0 += 4) {
        float4 w4 = *reinterpret_cast<const float4*>(wr + d0);
        a += qv[d0] * w4.x + qv[d0 + 1] * w4.y + qv[d0 + 2] * w4.z + qv[d0 + 3] * w4.w;
      }
      qwtmp[jj] = a;
    }
#pragma unroll
    for (int jj = 0; jj < 4; ++jj) vecB[tid + 256 * jj] = qwtmp[jj];
  }
  __syncthreads();

  {  // scores
    int t = tid & 63, ec = tid >> 6;
    const float* xr = X + ((size_t)b * NTT + t) * NE + ec * 256;
    float part = 0.f;
#pragma unroll 4
    for (int i = 0; i < 256; i += 4) {
      float4 x4 = *reinterpret_cast<const float4*>(xr + i);
      part += vecB[ec * 256 + i] * x4.x + vecB[ec * 256 + i + 1] * x4.y +
              vecB[ec * 256 + i + 2] * x4.z + vecB[ec * 256 + i + 3] * x4.w;
    }
    red[ec * 64 + t] = part;
  }
  __syncthreads();
  float sco = -INFINITY;
  if (tid < 64) {
    float s = (red[tid] + red[64 + tid] + red[128 + tid] + red[192 + tid]) * 0.125f;
    int idx = b * NTT + tid;
    bool valid = mask_i32 ? (((const int*)maskp)[idx] != 0)
                          : (((const unsigned char*)maskp)[idx] != 0);
    sco = valid ? s : -INFINITY;
  }
  __syncthreads();
  red[tid] = (tid < 64) ? sco : -INFINITY; __syncthreads();
  for (int o = 128; o; o >>= 1) { if (tid < o) red[tid] = fmaxf(red[tid], red[tid + o]); __syncthreads(); }
  float mx = red[0]; __syncthreads();
  float e = (tid < 64) ? __expf(sco - mx) : 0.f;
  red[tid] = e; __syncthreads();
  for (int o = 128; o; o >>= 1) { if (tid < o) red[tid] += red[tid + o]; __syncthreads(); }
  if (tid < 64) w_[tid] = e / red[0];
  __syncthreads();

  {  // wX[e] = sum_t w_[t] * X[b,t,e]
    float4 a = make_float4(0.f, 0.f, 0.f, 0.f);
    const float* xb = X + (size_t)b * NTT * NE + tid * 4;
    for (int t = 0; t < NTT; t += 4) {
#pragma unroll
      for (int j = 0; j < 4; ++j) {
        float4 x4 = *reinterpret_cast<const float4*>(xb + (size_t)(t + j) * NE);
        float w = w_[t + j];
        a.x += w * x4.x; a.y += w * x4.y; a.z += w * x4.z; a.w += w * x4.w;
      }
    }
    reinterpret_cast<float4*>(vecA)[tid] = a;
  }
  __syncthreads();

  {  // oe[d] = sum_e wX[e] * Wev[e, hh*64+d]
    int d4 = (tid & 15) * 4, ech = tid >> 4;
    const float* base = Wev + hh * 64 + d4;
    float4 a = make_float4(0.f, 0.f, 0.f, 0.f);
    for (int e = ech * 64; e < ech * 64 + 64; e += 8) {
      float4 w[8];
#pragma unroll
      for (int j = 0; j < 8; ++j)
        w[j] = *reinterpret_cast<const float4*>(base + (size_t)(e + j) * NE);
#pragma unroll
      for (int j = 0; j < 8; ++j) {
        float hv = vecA[e + j];
        a.x += hv * w[j].x; a.y += hv * w[j].y; a.z += hv * w[j].z; a.w += hv * w[j].w;
      }
    }
    vecB[ech * 64 + d4 + 0] = a.x; vecB[ech * 64 + d4 + 1] = a.y;
    vecB[ech * 64 + d4 + 2] = a.z; vecB[ech * 64 + d4 + 3] = a.w;
  }
  __syncthreads();
  if (tid < 64) {
    float s = 0.f;
#pragma unroll
    for (int c = 0; c < 16; ++c) s += vecB[c * 64 + tid];
    oe[tid] = s;
  }
  __syncthreads();

  {  // spart[hh][b][:] = oe @ Weo[hh*64.., :]
    int nb = tid * 4;
    const float* wp = Weo + (size_t)(hh * 64) * NE + nb;
    float4 acc = make_float4(0.f, 0.f, 0.f, 0.f);
    for (int d = 0; d < 64; d += 8) {
      float4 w[8];
#pragma unroll
      for (int j = 0; j < 8; ++j)
        w[j] = *reinterpret_cast<const float4*>(wp + (size_t)(d + j) * NE);
#pragma unroll
      for (int j = 0; j < 8; ++j) {
        float o = oe[d + j];
        acc.x += o * w[j].x; acc.y += o * w[j].y; acc.z += o * w[j].z; acc.w += o * w[j].w;
      }
    }
    *reinterpret_cast<float4*>(spart + ((size_t)hh * 8 + b) * 1024 + nb) = acc;
  }
}

// ---------------- reduce lm_head partials -> logits ----------------
__global__ __launch_bounds__(256) void reduce_logits(const float* __restrict__ P,
                                                     float* __restrict__ logits) {
  int r = blockIdx.x / 17, cc = blockIdx.x % 17;
  int col = cc * 1024 + threadIdx.x * 4;
  if (col >= NV) return;
  if (col + 3 < NV) {
    const float* base = P + (size_t)r * NVPAD + col;
    float4 acc = make_float4(0.f, 0.f, 0.f, 0.f);
    for (int ks = 0; ks < 16; ks += 8) {
      float4 w[8];
#pragma unroll
      for (int j = 0; j < 8; ++j)
        w[j] = *reinterpret_cast<const float4*>(base + (size_t)(ks + j) * 8 * NVPAD);
#pragma unroll
      for (int j = 0; j < 8; ++j) acc = f4add(acc, w[j]);
    }
    *reinterpret_cast<float4*>(logits + (size_t)r * NV + col) = acc;
  } else {
    for (int c = 0; c < 4 && col + c < NV; ++c) {
      float a = 0.f;
      for (int ks = 0; ks < 16; ++ks) a += P[((size_t)ks * 8 + r) * NVPAD + col + c];
      logits[(size_t)r * NV + col + c] = a;
    }
  }
}

extern "C" void kernel_launch(void* const* d_in, const int* in_sizes, int n_in,
                              void* d_out, int out_size, void* d_ws, size_t ws_size,
                              hipStream_t stream) {
  const float* enc_state = (const float*)d_in[0];
  const float* ast_in    = (const float*)d_in[1];
  const void* amask      = d_in[2];
  const int* prev = (const int*)d_in[3];
  const int* tix  = (const int*)d_in[4];
  const float* embed_tok = (const float*)d_in[5];
  const float* embed_pos = (const float*)d_in[6];
  const float* lnemb_s = (const float*)d_in[7];
  const float* lnemb_b = (const float*)d_in[8];
  const float* psb = (const float*)d_in[9];
  const float* Wsq = (const float*)d_in[10];
  const float* Wsk = (const float*)d_in[11];
  const float* Wsv = (const float*)d_in[12];
  const float* Wso = (const float*)d_in[13];
  const float* sls = (const float*)d_in[14];
  const float* slb = (const float*)d_in[15];
  const float* peb = (const float*)d_in[16];
  const float* Weq = (const float*)d_in[17];
  const float* Wek = (const float*)d_in[18];
  const float* Wev = (const float*)d_in[19];
  const float* Weo = (const float*)d_in[20];
  const float* els = (const float*)d_in[21];
  const float* elb = (const float*)d_in[22];
  const float* g0b = (const float*)d_in[23];
  const float* Wf0 = (const float*)d_in[24];
  const float* Wf1 = (const float*)d_in[25];
  const float* g1b = (const float*)d_in[26];
  const float* Wf2 = (const float*)d_in[27];
  const float* flb = (const float*)d_in[28];
  const float* Wlm = (const float*)d_in[29];

  float* ws = (float*)d_ws;
  float* logits = (float*)d_out;
  float* out_ast = logits + (size_t)NB * NV;

  copy_ast<<<4096, 256, 0, stream>>>((const float4*)ast_in, (float4*)out_ast,
                                     NL * 16 * NIMG * NE / 4);
  embed_kernel<<<NB, 256, 0, stream>>>(embed_tok, embed_pos, prev, tix, lnemb_b, lnemb_s,
                                       psb, ws + XBUF, ws + DH1);

  for (int l = 0; l < NL; ++l) {
    size_t wE = (size_t)l * NE * NE;
    size_t wG = (size_t)l * NE * NG;

    if (l > 0) {
      // x_l = x3_{l-1} + fc2 partials; h1 = LN(x_l) + psb_l
      ln_fc2<<<NB, 256, 0, stream>>>(ws + P_FC2, ws + DX3, psb + (size_t)l * NE,
                                     ws + XBUF, ws + DH1, 64);
    }
    {  // qkv partials
      MvPartP p{}; p.W0 = Wsk + wE; p.W1 = Wsv + wE; p.W2 = Wsq + wE;
      p.pout = ws + P_QKV; p.hsrc = ws + DH1;
      p.K = NE; p.N = NE; p.NPAD = NE; p.CB = 1; p.KS = 32;
      mv_part<<<3 * 32, 256, 0, stream>>>(p);
    }
    reduce_qkv<<<24, 256, 0, stream>>>(ws + P_QKV, ws + QSELF, ws + KVBUF,
                                       out_ast + (size_t)l * 16 * NIMG * NE, tix);
    attn_self<<<NB * NH, 256, 0, stream>>>(ws + QSELF, ws + KVBUF,
                                           ast_in + (size_t)l * 16 * NIMG * NE,
                                           tix, Wso + wE, ws + SSPART);
    ln_res_sum<<<NB, 256, 0, stream>>>(ws + XBUF, ws + SSPART, sls + (size_t)l * NE,
                                       slb + (size_t)l * NE, peb + (size_t)l * NE,
                                       ws + DX2, ws + DH2);
    cross_full<<<NB * NH, 256, 0, stream>>>(ws + DH2, Weq + wE, Wek + wE, Wev + wE,
                                            Weo + wE, enc_state, amask, ws + SEPART);
    ln_res_sum<<<NB, 256, 0, stream>>>(ws + DX2, ws + SEPART, els + (size_t)l * NE,
                                       elb + (size_t)l * NE, g0b + (size_t)l * NE,
                                       ws + DX3, ws + DH3);
    {  // fc0, fc1 partials
      MvPartP p{}; p.W0 = Wf0 + wG; p.W1 = Wf1 + wG;
      p.pout = ws + P_FC01; p.hsrc = ws + DH3;
      p.K = NE; p.N = NG; p.NPAD = NG; p.CB = 4; p.KS = 16;
      mv_part<<<2 * 4 * 16, 256, 0, stream>>>(p);
    }
    gelu_ln_sum<<<NB, 256, 0, stream>>>(ws + P_FC01, g1b + (size_t)l * NG, ws + DHG);
    {  // fc2 partials
      MvPartP p{}; p.W0 = Wf2 + (size_t)l * NG * NE;
      p.pout = ws + P_FC2; p.hsrc = ws + DHG;
      p.K = NG; p.N = NE; p.NPAD = NE; p.CB = 1; p.KS = 64;
      mv_part<<<64, 256, 0, stream>>>(p);
    }
  }
  // x4 = x3 + fc2 partials; hf = LN(x4) + flb
  ln_fc2<<<NB, 256, 0, stream>>>(ws + P_FC2, ws + DX3, flb, ws + XBUF, ws + DHF, 64);
  {  // lm_head partials
    MvPartP p{}; p.W0 = Wlm;
    p.pout = ws + P_LM; p.hsrc = ws + DHF;
    p.K = NE; p.N = NV; p.NPAD = NVPAD; p.CB = 17; p.KS = 16;
    mv_part<<<17 * 16, 256, 0, stream>>>(p);
  }
  reduce_logits<<<NB * 17, 256, 0, stream>>>(ws + P_LM, logits);
}